// Round 5
// baseline (15464.069 us; speedup 1.0000x reference)
//
#include <hip/hip_runtime.h>
#include <hip/hip_bf16.h>
#include <math.h>

#define Bb 64
#define Tt 512
#define Dd 1024
#define Uu 1024
#define NWG 64        // persistent workgroups
#define NTHR 512      // 8 waves
#define UPW 16        // u's per WG
#define ZLDX 65       // z row stride (65&31==1 -> bank=(row+col)&31, ~2-way free)

typedef __attribute__((ext_vector_type(8))) short bf16x8;
typedef __attribute__((ext_vector_type(4))) float f32x4;
typedef __attribute__((ext_vector_type(2))) float f32x2;

// ---- one-time prep -------------------------------------------------------

__global__ void cast_x_bf16(const float* __restrict__ in, __hip_bfloat16* __restrict__ out, int n4) {
  int i = blockIdx.x * blockDim.x + threadIdx.x;
  int stride = gridDim.x * blockDim.x;
  for (; i < n4; i += stride) {
    float4 v = reinterpret_cast<const float4*>(in)[i];
    __hip_bfloat16* o = out + 4 * (size_t)i;
    o[0] = __float2bfloat16(v.x);
    o[1] = __float2bfloat16(v.y);
    o[2] = __float2bfloat16(v.z);
    o[3] = __float2bfloat16(v.w);
  }
}

// Per-(WG j, wave w) contiguous 16384-elem weight blocks, matching the
// persistent kernel's fragment loads.
// w<4  (x-wave, gate w, 16 u, K=1024): idx = pc*1024 + k, src Wx[k][w*1024+j*16+pc]
// w>=4 (h-wave s=w-4: K-half s>>1, col-half s&1): idx = pc*512 + k,
//       pcg = (s&1)*32+pc, src Wh[(s>>1)*512+k][ (pcg>>4)*1024 + j*16 + (pcg&15) ]
__global__ void pack_w2(const float* __restrict__ Wx, const float* __restrict__ Wh,
                        __hip_bfloat16* __restrict__ pW2) {
  int blk = blockIdx.x;  // 0..511
  int j = blk >> 3, w = blk & 7;
  __hip_bfloat16* dst = pW2 + (size_t)blk * 16384;
  if (w < 4) {
    for (int e = threadIdx.x; e < 16384; e += 256) {
      int pc = e >> 10, k = e & 1023;
      dst[e] = __float2bfloat16(Wx[(size_t)k * 4096 + w * 1024 + j * 16 + pc]);
    }
  } else {
    int s = w - 4, kh = s >> 1, chh = s & 1;
    for (int e = threadIdx.x; e < 16384; e += 256) {
      int pc = e >> 9, k = e & 511;
      int pcg = chh * 32 + pc, g = pcg >> 4, uu = pcg & 15;
      dst[e] = __float2bfloat16(Wh[(size_t)(kh * 512 + k) * 4096 + g * 1024 + j * 16 + uu]);
    }
  }
}

// ---- persistent LSTM -----------------------------------------------------
// 64 WGs x 512 thr. WG j owns u in [j*16, j*16+16) -> 64 packed cols (4 gates).
// Waves 0..3: zx(t+1) = x_{t+1} @ Wx[:, gate w cols], full K (off critical path).
// Waves 4..7: wait on the 32 producer flags of their h K-half (replicated
// flag lines, <=16 readers each), then zh(t) partial.
// Epilogue: all 512 threads reduce zx+zh, gates, store out + h(t+1).
__launch_bounds__(NTHR, 2)
__global__ void lstm_persist(const __hip_bfloat16* __restrict__ xb,
                             const __hip_bfloat16* __restrict__ pW2,
                             const float* __restrict__ bias,
                             const float* __restrict__ h0,
                             const float* __restrict__ c0,
                             __hip_bfloat16* __restrict__ hb,  // [2][B][U]
                             float* __restrict__ out,
                             unsigned* __restrict__ flags) {   // [NWG][8 replicas][16]
  const int tid = threadIdx.x;
  const int wv = tid >> 6;
  const int lane = tid & 63;
  const int l15 = lane & 15;
  const int lk = lane >> 4;
  const int j = blockIdx.x;

  __shared__ float zx[2][Bb][ZLDX];  // double-buffered x partial (full K)
  __shared__ float zh[2][Bb][ZLDX];  // h partial per K-half

  // --- weight fragments into registers (held all 512 steps)
  bf16x8 wreg[32];
  {
    const __hip_bfloat16* wp = pW2 + (size_t)(j * 8 + wv) * 16384;
    if (wv < 4) {
#pragma unroll
      for (int kk = 0; kk < 32; ++kk)
        wreg[kk] = *reinterpret_cast<const bf16x8*>(wp + l15 * 1024 + kk * 32 + lk * 8);
    } else {
#pragma unroll
      for (int nt = 0; nt < 2; ++nt)
#pragma unroll
        for (int kk = 0; kk < 16; ++kk)
          wreg[nt * 16 + kk] =
              *reinterpret_cast<const bf16x8*>(wp + (nt * 16 + l15) * 512 + kk * 32 + lk * 8);
    }
#pragma unroll
    for (int i = 0; i < 32; ++i) asm volatile("" : "+v"(wreg[i]));
  }

  // --- epilogue ownership: one batch row, two adjacent u's
  const int eb = tid >> 3;         // 0..63
  const int eu = (tid & 7) * 2;    // 0..14
  const int u0 = j * UPW + eu;
  float bi[4][2];
#pragma unroll
  for (int g = 0; g < 4; ++g) {
    bi[g][0] = bias[g * Uu + u0];
    bi[g][1] = bias[g * Uu + u0 + 1];
  }
  float cr0 = c0[(size_t)eb * Uu + u0];
  float cr1 = c0[(size_t)eb * Uu + u0 + 1];

  // --- init h buffer 0 (system-scope write-through)
  unsigned* hb32 = (unsigned*)hb;
  {
    union { __hip_bfloat162 v; unsigned u; } pk;
    pk.v.x = __float2bfloat16(h0[(size_t)eb * Uu + u0]);
    pk.v.y = __float2bfloat16(h0[(size_t)eb * Uu + u0 + 1]);
    __hip_atomic_store(&hb32[((size_t)eb * Uu + u0) >> 1], pk.u,
                       __ATOMIC_RELAXED, __HIP_MEMORY_SCOPE_SYSTEM);
  }

  // --- prologue: zx(0) into buffer 0
  if (wv < 4) {
    f32x4 acc[4];
#pragma unroll
    for (int mt = 0; mt < 4; ++mt) acc[mt] = (f32x4){0.f, 0.f, 0.f, 0.f};
#pragma unroll
    for (int kk = 0; kk < 32; ++kk) {
      bf16x8 af[4];
#pragma unroll
      for (int mt = 0; mt < 4; ++mt) {
        int m = mt * 16 + l15;
        af[mt] = *reinterpret_cast<const bf16x8*>(xb + (size_t)m * Tt * Dd + kk * 32 + lk * 8);
      }
#pragma unroll
      for (int mt = 0; mt < 4; ++mt)
        acc[mt] = __builtin_amdgcn_mfma_f32_16x16x32_bf16(af[mt], wreg[kk], acc[mt], 0, 0, 0);
    }
#pragma unroll
    for (int mt = 0; mt < 4; ++mt)
#pragma unroll
      for (int q = 0; q < 4; ++q)
        zx[0][mt * 16 + lk * 4 + q][wv * 16 + l15] = acc[mt][q];
  }

  for (int t = 0; t < Tt; ++t) {
    // joins epilogue(t-1); each wave's vmcnt drains -> h(t) stores visible
    __syncthreads();

    // publish "h(t) ready" to 8 replica lines (one vector store, 8 lanes)
    if (tid < 8)
      __hip_atomic_store(&flags[(j * 8 + tid) * 16], (unsigned)(t + 1),
                         __ATOMIC_RELAXED, __HIP_MEMORY_SCOPE_SYSTEM);

    if (wv < 4) {
      // ---- x part for step t+1 (no h dependency; overlaps h-wave waits)
      const int xt = (t + 1 < Tt) ? t + 1 : t;
      f32x4 acc[4];
#pragma unroll
      for (int mt = 0; mt < 4; ++mt) acc[mt] = (f32x4){0.f, 0.f, 0.f, 0.f};
      const __hip_bfloat16* asrc = xb + (size_t)xt * Dd;
#pragma unroll
      for (int kk = 0; kk < 32; ++kk) {
        bf16x8 af[4];
#pragma unroll
        for (int mt = 0; mt < 4; ++mt) {
          int m = mt * 16 + l15;
          af[mt] = *reinterpret_cast<const bf16x8*>(asrc + (size_t)m * Tt * Dd + kk * 32 + lk * 8);
        }
#pragma unroll
        for (int mt = 0; mt < 4; ++mt)
          acc[mt] = __builtin_amdgcn_mfma_f32_16x16x32_bf16(af[mt], wreg[kk], acc[mt], 0, 0, 0);
      }
      float (*zdst)[ZLDX] = zx[(t + 1) & 1];
#pragma unroll
      for (int mt = 0; mt < 4; ++mt)
#pragma unroll
        for (int q = 0; q < 4; ++q)
          zdst[mt * 16 + lk * 4 + q][wv * 16 + l15] = acc[mt][q];
    } else {
      // ---- wait directly on the 32 producers of this K-half, then h part
      const int s = wv - 4, kh = s >> 1, chh = s & 1;
      if (lane < 32) {
        const unsigned* fp = &flags[((kh * 32 + lane) * 8 + (j & 7)) * 16];
        while (__hip_atomic_load(fp, __ATOMIC_RELAXED, __HIP_MEMORY_SCOPE_SYSTEM) <
               (unsigned)(t + 1))
          __builtin_amdgcn_s_sleep(2);
      }

      const __hip_bfloat16* hcur = hb + (size_t)(t & 1) * (Bb * Uu);
      f32x4 acc[4][2];
#pragma unroll
      for (int mt = 0; mt < 4; ++mt)
#pragma unroll
        for (int nt = 0; nt < 2; ++nt) acc[mt][nt] = (f32x4){0.f, 0.f, 0.f, 0.f};
#pragma unroll
      for (int kk = 0; kk < 16; ++kk) {
        bf16x8 af[4];
#pragma unroll
        for (int mt = 0; mt < 4; ++mt) {
          int m = mt * 16 + l15;
          const unsigned long long* p = (const unsigned long long*)(hcur + (size_t)m * Uu +
                                                                    kh * 512 + kk * 32 + lk * 8);
          union { bf16x8 v; unsigned long long q[2]; } au;
          au.q[0] = __hip_atomic_load(p, __ATOMIC_RELAXED, __HIP_MEMORY_SCOPE_SYSTEM);
          au.q[1] = __hip_atomic_load(p + 1, __ATOMIC_RELAXED, __HIP_MEMORY_SCOPE_SYSTEM);
          af[mt] = au.v;
        }
#pragma unroll
        for (int mt = 0; mt < 4; ++mt) {
          acc[mt][0] = __builtin_amdgcn_mfma_f32_16x16x32_bf16(af[mt], wreg[kk], acc[mt][0], 0, 0, 0);
          acc[mt][1] = __builtin_amdgcn_mfma_f32_16x16x32_bf16(af[mt], wreg[16 + kk], acc[mt][1], 0, 0, 0);
        }
      }
      float (*zdst)[ZLDX] = zh[kh];
#pragma unroll
      for (int mt = 0; mt < 4; ++mt)
#pragma unroll
        for (int nt = 0; nt < 2; ++nt)
#pragma unroll
          for (int q = 0; q < 4; ++q)
            zdst[mt * 16 + lk * 4 + q][chh * 32 + nt * 16 + l15] = acc[mt][nt][q];
    }
    __syncthreads();

    // ---- epilogue(t): z = zx + zh0 + zh1 + bias; gates; emit
    unsigned* hnxt32 = hb32 + ((size_t)((t + 1) & 1) * (Bb * Uu) >> 1);
    float zc[4][2];
#pragma unroll
    for (int g = 0; g < 4; ++g)
#pragma unroll
      for (int d = 0; d < 2; ++d) {
        int c = g * 16 + eu + d;
        zc[g][d] = zx[t & 1][eb][c] + zh[0][eb][c] + zh[1][eb][c] + bi[g][d];
      }
    float hv0, hv1;
    {
      float ig = 1.f / (1.f + __expf(-zc[0][0]));
      float fg = 1.f / (1.f + __expf(-zc[1][0]));
      float gg = tanhf(zc[2][0]);
      float og = 1.f / (1.f + __expf(-zc[3][0]));
      cr0 = fg * cr0 + ig * gg;
      hv0 = og * tanhf(cr0);
    }
    {
      float ig = 1.f / (1.f + __expf(-zc[0][1]));
      float fg = 1.f / (1.f + __expf(-zc[1][1]));
      float gg = tanhf(zc[2][1]);
      float og = 1.f / (1.f + __expf(-zc[3][1]));
      cr1 = fg * cr1 + ig * gg;
      hv1 = og * tanhf(cr1);
    }
    f32x2 o2 = {hv0, hv1};
    __builtin_nontemporal_store(o2, (f32x2*)(out + ((size_t)eb * Tt + t) * Uu + u0));
    {
      union { __hip_bfloat162 v; unsigned u; } pk;
      pk.v.x = __float2bfloat16(hv0);
      pk.v.y = __float2bfloat16(hv1);
      __hip_atomic_store(&hnxt32[((size_t)eb * Uu + u0) >> 1], pk.u,
                         __ATOMIC_RELAXED, __HIP_MEMORY_SCOPE_SYSTEM);
    }
  }
}

// ---- launch --------------------------------------------------------------

extern "C" void kernel_launch(void* const* d_in, const int* in_sizes, int n_in,
                              void* d_out, int out_size, void* d_ws, size_t ws_size,
                              hipStream_t stream) {
  const float* x = (const float*)d_in[0];
  const float* h0 = (const float*)d_in[1];
  const float* c0 = (const float*)d_in[2];
  const float* Wx = (const float*)d_in[3];
  const float* Wh = (const float*)d_in[4];
  const float* bias = (const float*)d_in[5];
  float* out = (float*)d_out;

  char* ws = (char*)d_ws;
  size_t off = 0;
  __hip_bfloat16* xb = (__hip_bfloat16*)(ws + off);  off += (size_t)Bb * Tt * Dd * 2;     // 64 MB
  __hip_bfloat16* pW2 = (__hip_bfloat16*)(ws + off); off += (size_t)NWG * 8 * 16384 * 2;  // 16 MB
  __hip_bfloat16* hb = (__hip_bfloat16*)(ws + off);  off += (size_t)2 * Bb * Uu * 2;      // 256 KB
  unsigned* flags = (unsigned*)(ws + off);           off += (size_t)NWG * 8 * 64;         // 32 KB

  cast_x_bf16<<<4096, 256, 0, stream>>>(x, xb, Bb * Tt * Dd / 4);
  pack_w2<<<NWG * 8, 256, 0, stream>>>(Wx, Wh, pW2);
  hipMemsetAsync(flags, 0, (size_t)NWG * 8 * 64, stream);

  lstm_persist<<<NWG, NTHR, 0, stream>>>(xb, pW2, bias, h0, c0, hb, out, flags);
}

// Round 6
// 6913.630 us; speedup vs baseline: 2.2368x; 2.2368x over previous
//
#include <hip/hip_runtime.h>
#include <hip/hip_bf16.h>
#include <math.h>

#define Bb 64
#define Tt 512
#define Dd 1024
#define Uu 1024
#define NWG 128      // persistent workgroups
#define UPW 8        // u's per WG
#define NCOL 32      // packed cols per WG = 4 gates * UPW
#define KTOT 2048    // D + U
#define KW 512       // K-slice per wave
#define ZLD 34

typedef __attribute__((ext_vector_type(8))) short bf16x8;
typedef __attribute__((ext_vector_type(4))) float f32x4;
typedef __attribute__((ext_vector_type(2))) float f32x2;

// dynamic LDS carve: wlds (h-weights) 65536 B | zx 2*2*64*34*4 = 69632 B | zh 2*64*34*4 = 17408 B
#define WLDS_ELEMS 16384              // per h-wave slice (bf16)
#define ZX_OFF 65536
#define ZH_OFF (65536 + 69632)
#define DYN_LDS (65536 + 69632 + 17408)

// ---- one-time prep -------------------------------------------------------

__global__ void cast_x_bf16(const float* __restrict__ in, __hip_bfloat16* __restrict__ out, int n4) {
  int i = blockIdx.x * blockDim.x + threadIdx.x;
  int stride = gridDim.x * blockDim.x;
  for (; i < n4; i += stride) {
    float4 v = reinterpret_cast<const float4*>(in)[i];
    __hip_bfloat16* o = out + 4 * (size_t)i;
    o[0] = __float2bfloat16(v.x);
    o[1] = __float2bfloat16(v.y);
    o[2] = __float2bfloat16(v.z);
    o[3] = __float2bfloat16(v.w);
  }
}

// in: fp32 [K][4096] (Wx or Wh). out packed: pWT[j][pc][k], col=g*1024+j*8+uu, pc=g*8+uu.
__global__ void pack_w(const float* __restrict__ in, __hip_bfloat16* __restrict__ pWT, int koff) {
  __shared__ float tile[32][33];
  int n0 = blockIdx.x * 32, k0 = blockIdx.y * 32;
  int tx = threadIdx.x, ty = threadIdx.y;
#pragma unroll
  for (int p = 0; p < 4; ++p) {
    int r = ty + p * 8;
    tile[r][tx] = in[(size_t)(k0 + r) * (4 * Uu) + n0 + tx];
  }
  __syncthreads();
#pragma unroll
  for (int p = 0; p < 4; ++p) {
    int r = ty + p * 8;
    int col = n0 + r;
    int j = (col & (Uu - 1)) >> 3;
    int g = col >> 10;
    int uu = col & 7;
    pWT[((size_t)(j * NCOL + g * UPW + uu)) * KTOT + koff + k0 + tx] = __float2bfloat16(tile[tx][r]);
  }
}

// ---- pipelined h load macros ---------------------------------------------
#define H_ISSUE(ARR, bk)                                                          \
  {                                                                               \
    _Pragma("unroll") for (int q = 0; q < 4; ++q) {                               \
      _Pragma("unroll") for (int mt = 0; mt < 4; ++mt) {                          \
        asm volatile("global_load_dwordx4 %0, %1, off offset:%2 sc0 sc1"          \
                     : "=v"(ARR[q * 4 + mt])                                      \
                     : "v"(haddr[mt]), "i"((((bk) * 4 + q) * 64))                 \
                     : "memory");                                                 \
      }                                                                           \
    }                                                                             \
  }

#define H_CONS(ARR, bk)                                                           \
  {                                                                               \
    _Pragma("unroll") for (int q = 0; q < 4; ++q) {                               \
      const int kk = (bk) * 4 + q;                                                \
      bf16x8 w0 = *reinterpret_cast<const bf16x8*>(                               \
          &wlds[kh * WLDS_ELEMS + ((0 * 16 + kk) * 16 + l15) * 32 + lk * 8]);     \
      bf16x8 w1 = *reinterpret_cast<const bf16x8*>(                               \
          &wlds[kh * WLDS_ELEMS + ((1 * 16 + kk) * 16 + l15) * 32 + lk * 8]);     \
      _Pragma("unroll") for (int mt = 0; mt < 4; ++mt) {                          \
        bf16x8 af = __builtin_bit_cast(bf16x8, ARR[q * 4 + mt]);                  \
        acc[mt][0] = __builtin_amdgcn_mfma_f32_16x16x32_bf16(af, w0, acc[mt][0], 0, 0, 0); \
        acc[mt][1] = __builtin_amdgcn_mfma_f32_16x16x32_bf16(af, w1, acc[mt][1], 0, 0, 0); \
      }                                                                           \
    }                                                                             \
  }

#define WAITV(n)                                             \
  do {                                                       \
    asm volatile("s_waitcnt vmcnt(" #n ")" ::: "memory");    \
    __builtin_amdgcn_sched_barrier(0);                       \
  } while (0)

// ---- persistent LSTM -----------------------------------------------------
// 128 WGs x 256 thr. WG j owns u in [j*8, j*8+8) -> 32 packed cols (4 gates).
// Waves 0,1: zx(t+1) over K-half each (Wx frags from global/L2).
// Waves 2,3: sync (aggregated flags -> replicated release -> LDS gate),
//            then zh(t): h via 2-deep pipelined 16B sc-loads, Wh from LDS.
__launch_bounds__(256, 1)
__global__ void lstm_persist(const __hip_bfloat16* __restrict__ xb,
                             const __hip_bfloat16* __restrict__ pWT,
                             const float* __restrict__ bias,
                             const float* __restrict__ h0,
                             const float* __restrict__ c0,
                             __hip_bfloat16* __restrict__ hb,  // [2][B][U]
                             float* __restrict__ out,
                             unsigned* __restrict__ flags,     // [NWG][16] 64B lines
                             unsigned* __restrict__ rel) {     // [16][16] replicas
  extern __shared__ __align__(16) char smem[];
  __hip_bfloat16* wlds = (__hip_bfloat16*)smem;
  float* zxb = (float*)(smem + ZX_OFF);  // [2][2][Bb][ZLD]
  float* zhb = (float*)(smem + ZH_OFF);  // [2][Bb][ZLD]
  __shared__ unsigned gate;

  const int tid = threadIdx.x;
  const int wv = tid >> 6;
  const int lane = tid & 63;
  const int l15 = lane & 15;
  const int lk = lane >> 4;
  const int j = blockIdx.x;

#define ZX(buf, w, b, c) zxb[((((buf)*2 + (w)) * Bb + (b)) * ZLD) + (c)]
#define ZH(w, b, c) zhb[(((w)*Bb + (b)) * ZLD) + (c)]

  // --- copy this WG's Wh slices into LDS (persist across all 512 steps)
  if (wv >= 2) {
    const int kh = wv - 2;
    const __hip_bfloat16* wp = pWT + (size_t)j * NCOL * KTOT + 1024 + kh * KW;
#pragma unroll
    for (int nt = 0; nt < 2; ++nt)
#pragma unroll
      for (int kk = 0; kk < 16; ++kk) {
        bf16x8 v = *reinterpret_cast<const bf16x8*>(wp + (size_t)(nt * 16 + l15) * KTOT +
                                                    kk * 32 + lk * 8);
        *reinterpret_cast<bf16x8*>(
            &wlds[kh * WLDS_ELEMS + ((nt * 16 + kk) * 16 + l15) * 32 + lk * 8]) = v;
      }
  }
  if (tid == 0) gate = 0;

  // --- epilogue ownership: one batch row, two adjacent u's
  const int eb = tid >> 2;
  const int eu = (tid & 3) * 2;
  const int u0 = j * UPW + eu;
  float bi0[4], bi1[4];
#pragma unroll
  for (int g = 0; g < 4; ++g) {
    bi0[g] = bias[g * Uu + u0];
    bi1[g] = bias[g * Uu + u0 + 1];
  }
  float cr0 = c0[(size_t)eb * Uu + u0];
  float cr1 = c0[(size_t)eb * Uu + u0 + 1];

  // --- init h buffer 0 (system-scope write-through)
  unsigned* hb32 = (unsigned*)hb;
  {
    union { __hip_bfloat162 v; unsigned u; } pk;
    pk.v.x = __float2bfloat16(h0[(size_t)eb * Uu + u0]);
    pk.v.y = __float2bfloat16(h0[(size_t)eb * Uu + u0 + 1]);
    __hip_atomic_store(&hb32[((size_t)eb * Uu + u0) >> 1], pk.u,
                       __ATOMIC_RELAXED, __HIP_MEMORY_SCOPE_SYSTEM);
  }
  __syncthreads();  // wlds + gate ready

  // --- prologue: zx(0) into buffer 0
  if (wv < 2) {
    f32x4 accx[4][2];
#pragma unroll
    for (int mt = 0; mt < 4; ++mt)
#pragma unroll
      for (int nt = 0; nt < 2; ++nt) accx[mt][nt] = (f32x4){0.f, 0.f, 0.f, 0.f};
    const __hip_bfloat16* asrc = xb + (size_t)wv * KW;
    const __hip_bfloat16* wpx = pWT + (size_t)j * NCOL * KTOT + wv * KW;
#pragma unroll
    for (int kk = 0; kk < 16; ++kk) {
      bf16x8 wx0 = *reinterpret_cast<const bf16x8*>(wpx + (size_t)(0 * 16 + l15) * KTOT + kk * 32 + lk * 8);
      bf16x8 wx1 = *reinterpret_cast<const bf16x8*>(wpx + (size_t)(1 * 16 + l15) * KTOT + kk * 32 + lk * 8);
      bf16x8 af[4];
#pragma unroll
      for (int mt = 0; mt < 4; ++mt) {
        int m = mt * 16 + l15;
        af[mt] = *reinterpret_cast<const bf16x8*>(asrc + (size_t)m * Tt * Dd + kk * 32 + lk * 8);
      }
#pragma unroll
      for (int mt = 0; mt < 4; ++mt) {
        accx[mt][0] = __builtin_amdgcn_mfma_f32_16x16x32_bf16(af[mt], wx0, accx[mt][0], 0, 0, 0);
        accx[mt][1] = __builtin_amdgcn_mfma_f32_16x16x32_bf16(af[mt], wx1, accx[mt][1], 0, 0, 0);
      }
    }
#pragma unroll
    for (int mt = 0; mt < 4; ++mt)
#pragma unroll
      for (int nt = 0; nt < 2; ++nt)
#pragma unroll
        for (int q = 0; q < 4; ++q)
          ZX(0, wv, mt * 16 + lk * 4 + q, nt * 16 + l15) = accx[mt][nt][q];
  }

  for (int t = 0; t < Tt; ++t) {
    // joins epilogue(t-1); drains every wave's vmcnt -> h(t) stores ack'd
    __syncthreads();

    const unsigned want = (unsigned)(t + 1);
    if (tid == 0)
      __hip_atomic_store(&flags[j * 16], want, __ATOMIC_RELAXED, __HIP_MEMORY_SCOPE_SYSTEM);

    if (wv < 2) {
      // ---- x part for step t+1 (off critical path)
      const int xt = (t + 1 < Tt) ? t + 1 : t;
      f32x4 accx[4][2];
#pragma unroll
      for (int mt = 0; mt < 4; ++mt)
#pragma unroll
        for (int nt = 0; nt < 2; ++nt) accx[mt][nt] = (f32x4){0.f, 0.f, 0.f, 0.f};
      const __hip_bfloat16* asrc = xb + (size_t)xt * Dd + (size_t)wv * KW;
      const __hip_bfloat16* wpx = pWT + (size_t)j * NCOL * KTOT + wv * KW;
#pragma unroll
      for (int kk = 0; kk < 16; ++kk) {
        bf16x8 wx0 = *reinterpret_cast<const bf16x8*>(wpx + (size_t)(0 * 16 + l15) * KTOT + kk * 32 + lk * 8);
        bf16x8 wx1 = *reinterpret_cast<const bf16x8*>(wpx + (size_t)(1 * 16 + l15) * KTOT + kk * 32 + lk * 8);
        bf16x8 af[4];
#pragma unroll
        for (int mt = 0; mt < 4; ++mt) {
          int m = mt * 16 + l15;
          af[mt] = *reinterpret_cast<const bf16x8*>(asrc + (size_t)m * Tt * Dd + kk * 32 + lk * 8);
        }
#pragma unroll
        for (int mt = 0; mt < 4; ++mt) {
          accx[mt][0] = __builtin_amdgcn_mfma_f32_16x16x32_bf16(af[mt], wx0, accx[mt][0], 0, 0, 0);
          accx[mt][1] = __builtin_amdgcn_mfma_f32_16x16x32_bf16(af[mt], wx1, accx[mt][1], 0, 0, 0);
        }
      }
      const int buf = (t + 1) & 1;
#pragma unroll
      for (int mt = 0; mt < 4; ++mt)
#pragma unroll
        for (int nt = 0; nt < 2; ++nt)
#pragma unroll
          for (int q = 0; q < 4; ++q)
            ZX(buf, wv, mt * 16 + lk * 4 + q, nt * 16 + l15) = accx[mt][nt][q];
    } else {
      // ---- sync: flags -> (WG0) -> replicated release -> LDS gate
      if (wv == 2) {
        if (j == 0) {
          const unsigned* f0 = &flags[lane * 16];
          const unsigned* f1 = &flags[(64 + lane) * 16];
          while (__hip_atomic_load(f0, __ATOMIC_RELAXED, __HIP_MEMORY_SCOPE_SYSTEM) < want)
            __builtin_amdgcn_s_sleep(1);
          while (__hip_atomic_load(f1, __ATOMIC_RELAXED, __HIP_MEMORY_SCOPE_SYSTEM) < want)
            __builtin_amdgcn_s_sleep(1);
          if (lane < 16)
            __hip_atomic_store(&rel[lane * 16], want, __ATOMIC_RELAXED, __HIP_MEMORY_SCOPE_SYSTEM);
        } else {
          if (lane == 0) {
            const unsigned* rp = &rel[(j & 15) * 16];
            while (__hip_atomic_load(rp, __ATOMIC_RELAXED, __HIP_MEMORY_SCOPE_SYSTEM) < want)
              __builtin_amdgcn_s_sleep(1);
          }
        }
        if (lane == 0)
          __hip_atomic_store(&gate, want, __ATOMIC_RELAXED, __HIP_MEMORY_SCOPE_WORKGROUP);
      } else {
        while (__hip_atomic_load(&gate, __ATOMIC_RELAXED, __HIP_MEMORY_SCOPE_WORKGROUP) < want)
          __builtin_amdgcn_s_sleep(1);
      }
      __builtin_amdgcn_sched_barrier(0);

      // ---- h part: 2-deep pipelined 16B system-scope loads, Wh from LDS
      const int kh = wv - 2;
      const __hip_bfloat16* hcur = hb + (size_t)(t & 1) * (Bb * Uu);
      unsigned long long haddr[4];
#pragma unroll
      for (int mt = 0; mt < 4; ++mt)
        haddr[mt] = (unsigned long long)(hcur + (size_t)(mt * 16 + l15) * Uu + kh * KW) + lk * 16;

      f32x4 hs0[16], hs1[16];
      f32x4 acc[4][2];
#pragma unroll
      for (int mt = 0; mt < 4; ++mt)
#pragma unroll
        for (int nt = 0; nt < 2; ++nt) acc[mt][nt] = (f32x4){0.f, 0.f, 0.f, 0.f};

      H_ISSUE(hs0, 0)
      H_ISSUE(hs1, 1)
      WAITV(16);
      H_CONS(hs0, 0)
      H_ISSUE(hs0, 2)
      WAITV(16);
      H_CONS(hs1, 1)
      H_ISSUE(hs1, 3)
      WAITV(16);
      H_CONS(hs0, 2)
      WAITV(0);
      H_CONS(hs1, 3)

#pragma unroll
      for (int mt = 0; mt < 4; ++mt)
#pragma unroll
        for (int nt = 0; nt < 2; ++nt)
#pragma unroll
          for (int q = 0; q < 4; ++q)
            ZH(kh, mt * 16 + lk * 4 + q, nt * 16 + l15) = acc[mt][nt][q];
    }
    __syncthreads();

    // ---- epilogue(t): z = zx(t) + zh0 + zh1 + bias; gates; emit
    unsigned* hnxt32 = hb32 + ((size_t)((t + 1) & 1) * (Bb * Uu) >> 1);
    const int buf = t & 1;
    f32x2 zz[4];
#pragma unroll
    for (int g = 0; g < 4; ++g) {
      int cc = g * UPW + eu;
      f32x2 s = *reinterpret_cast<const f32x2*>(&ZX(buf, 0, eb, cc));
      f32x2 v1 = *reinterpret_cast<const f32x2*>(&ZX(buf, 1, eb, cc));
      f32x2 v2 = *reinterpret_cast<const f32x2*>(&ZH(0, eb, cc));
      f32x2 v3 = *reinterpret_cast<const f32x2*>(&ZH(1, eb, cc));
      s.x += v1.x + v2.x + v3.x;
      s.y += v1.y + v2.y + v3.y;
      zz[g] = s;
    }
    float hv0, hv1;
    {
      float ig = 1.f / (1.f + __expf(-(zz[0].x + bi0[0])));
      float fg = 1.f / (1.f + __expf(-(zz[1].x + bi0[1])));
      float gg = tanhf(zz[2].x + bi0[2]);
      float og = 1.f / (1.f + __expf(-(zz[3].x + bi0[3])));
      cr0 = fg * cr0 + ig * gg;
      hv0 = og * tanhf(cr0);
    }
    {
      float ig = 1.f / (1.f + __expf(-(zz[0].y + bi1[0])));
      float fg = 1.f / (1.f + __expf(-(zz[1].y + bi1[1])));
      float gg = tanhf(zz[2].y + bi1[2]);
      float og = 1.f / (1.f + __expf(-(zz[3].y + bi1[3])));
      cr1 = fg * cr1 + ig * gg;
      hv1 = og * tanhf(cr1);
    }
    f32x2 o2 = {hv0, hv1};
    __builtin_nontemporal_store(o2, (f32x2*)(out + ((size_t)eb * Tt + t) * Uu + u0));
    {
      union { __hip_bfloat162 v; unsigned u; } pk;
      pk.v.x = __float2bfloat16(hv0);
      pk.v.y = __float2bfloat16(hv1);
      __hip_atomic_store(&hnxt32[((size_t)eb * Uu + u0) >> 1], pk.u,
                         __ATOMIC_RELAXED, __HIP_MEMORY_SCOPE_SYSTEM);
    }
  }
}

// ---- launch --------------------------------------------------------------

extern "C" void kernel_launch(void* const* d_in, const int* in_sizes, int n_in,
                              void* d_out, int out_size, void* d_ws, size_t ws_size,
                              hipStream_t stream) {
  const float* x = (const float*)d_in[0];
  const float* h0 = (const float*)d_in[1];
  const float* c0 = (const float*)d_in[2];
  const float* Wx = (const float*)d_in[3];
  const float* Wh = (const float*)d_in[4];
  const float* bias = (const float*)d_in[5];
  float* out = (float*)d_out;

  char* ws = (char*)d_ws;
  size_t off = 0;
  __hip_bfloat16* xb = (__hip_bfloat16*)(ws + off);  off += (size_t)Bb * Tt * Dd * 2;       // 64 MB
  __hip_bfloat16* pWT = (__hip_bfloat16*)(ws + off); off += (size_t)NWG * NCOL * KTOT * 2;  // 16 MB
  __hip_bfloat16* hb = (__hip_bfloat16*)(ws + off);  off += (size_t)2 * Bb * Uu * 2;        // 256 KB
  unsigned* flags = (unsigned*)(ws + off);           off += (size_t)NWG * 64;               // 8 KB
  unsigned* rel = (unsigned*)(ws + off);             off += (size_t)16 * 64;                // 1 KB

  hipFuncSetAttribute((const void*)lstm_persist,
                      hipFuncAttributeMaxDynamicSharedMemorySize, DYN_LDS);

  cast_x_bf16<<<4096, 256, 0, stream>>>(x, xb, Bb * Tt * Dd / 4);
  pack_w<<<dim3(4 * Uu / 32, Dd / 32), dim3(32, 8), 0, stream>>>(Wx, pWT, 0);
  pack_w<<<dim3(4 * Uu / 32, Uu / 32), dim3(32, 8), 0, stream>>>(Wh, pWT, Dd);
  hipMemsetAsync(flags, 0, (size_t)NWG * 64 + 16 * 64, stream);

  lstm_persist<<<NWG, 256, DYN_LDS, stream>>>(xb, pWT, bias, h0, c0, hb, out, flags, rel);
}